// Round 1
// baseline (4955.487 us; speedup 1.0000x reference)
//
#include <hip/hip_runtime.h>
#include <math.h>

// ---------------- constants ----------------
#define SEQ 128
#define BATCH 256
#define INPUT 300
#define HIDDEN 1024
#define NG 4096              // 4*HIDDEN, gate-interleaved: n' = 4*j + gate
#define KH 1024
#define KXP 320              // x K padded 300->320
#define KT 1344              // KH + KXP
#define NKT 42               // KT/32 k-tiles
#define KTH 32               // KH/32 h k-tiles
#define NKTH 32              // head k-tiles (K=1024)
#define LINEARN 1024
#define WROW 1032            // W_hh LDS row stride in shorts (1024 + 8 pad: 2064B -> 4-bank shift/row, 2-way = free)

typedef __attribute__((ext_vector_type(8))) short short8;
typedef __attribute__((ext_vector_type(4))) float floatx4;

__device__ __forceinline__ float sigf(float x)     { return 1.f / (1.f + __expf(-x)); }
__device__ __forceinline__ float tanhfast(float x) { return 2.f / (1.f + __expf(-2.f * x)) - 1.f; }

__device__ __forceinline__ unsigned short bf16_rne(float f) {
  unsigned u = __float_as_uint(f);
  u += 0x7FFFu + ((u >> 16) & 1u);
  return (unsigned short)(u >> 16);
}
__device__ __forceinline__ float bf16f(unsigned short s) {
  return __uint_as_float(((unsigned)s) << 16);
}

__device__ __forceinline__ void mfma3(floatx4& acc, short8 ah, short8 al, short8 bh, short8 bl) {
  acc = __builtin_amdgcn_mfma_f32_16x16x32_bf16(ah, bh, acc, 0, 0, 0);
  acc = __builtin_amdgcn_mfma_f32_16x16x32_bf16(ah, bl, acc, 0, 0, 0);
  acc = __builtin_amdgcn_mfma_f32_16x16x32_bf16(al, bh, acc, 0, 0, 0);
}
// W kept at bf16 (hi only); A split hi/lo corrects the h/x quantization.
__device__ __forceinline__ void mfma2(floatx4& acc, short8 ah, short8 al, short8 bh) {
  acc = __builtin_amdgcn_mfma_f32_16x16x32_bf16(ah, bh, acc, 0, 0, 0);
  acc = __builtin_amdgcn_mfma_f32_16x16x32_bf16(al, bh, acc, 0, 0, 0);
}

// ---------------- zero ----------------
__global__ __launch_bounds__(256) void zero_ws(float4* p, int n4) {
  int i = blockIdx.x * 256 + threadIdx.x;
  if (i < n4) p[i] = make_float4(0.f, 0.f, 0.f, 0.f);
}

// ---------------- weight pack: gate-interleave + pad, bf16 hi only ----------------
__global__ __launch_bounds__(256) void pack_w(
    const float* __restrict__ W_ih, const float* __restrict__ W_hh,
    unsigned short* __restrict__ Wph)
{
  int id = blockIdx.x * 256 + threadIdx.x;
  if (id >= NG * KT) return;
  int n = id / KT;
  int k = id - n * KT;
  int j = n >> 2, g = n & 3;
  int srow = g * HIDDEN + j;
  float w = 0.f;
  if (k < KH) w = W_hh[(size_t)srow * HIDDEN + k];
  else if (k - KH < INPUT) w = W_ih[(size_t)srow * INPUT + (k - KH)];
  Wph[id] = bf16_rne(w);
}

__global__ __launch_bounds__(256) void pack_bias(
    const float* __restrict__ b_ih, const float* __restrict__ b_hh,
    float* __restrict__ biasp)
{
  int n = blockIdx.x * 256 + threadIdx.x;
  if (n >= NG) return;
  int j = n >> 2, g = n & 3;
  int s = g * HIDDEN + j;
  biasp[n] = b_ih[s] + b_hh[s];
}

// ---------------- pack all x timesteps to bf16 hi/lo, padded 300->320 ----------------
__global__ __launch_bounds__(256) void pack_x(
    const float* __restrict__ x, unsigned short* __restrict__ xph,
    unsigned short* __restrict__ xpl)
{
  int id = blockIdx.x * 256 + threadIdx.x;
  if (id >= SEQ * BATCH * KXP) return;
  int row = id / KXP;
  int k = id - row * KXP;
  float v = (k < INPUT) ? x[(size_t)row * INPUT + k] : 0.f;
  unsigned short hi = bf16_rne(v);
  xph[id] = hi;
  xpl[id] = bf16_rne(v - bf16f(hi));
}

// ---------------- pack W1 (head) hi/lo ----------------
__global__ __launch_bounds__(256) void pack_w1(
    const float* __restrict__ W1, unsigned short* __restrict__ W1ph,
    unsigned short* __restrict__ W1pl)
{
  int id = blockIdx.x * 256 + threadIdx.x;
  if (id >= LINEARN * HIDDEN) return;
  float w = W1[id];
  unsigned short hi = bf16_rne(w);
  W1ph[id] = hi;
  W1pl[id] = bf16_rne(w - bf16f(hi));
}

// ---------------- persistent LSTM: all 128 steps in one kernel ----------------
// 256 blocks (1/CU, pinned by 148.7KB LDS), each owns a fixed 64x64 gate tile.
// W_hh tile resident in LDS (loaded once), W_ih tile in 80 VGPRs, bias in 2 VGPRs,
// cell state c in 4 VGPRs/thread. A (h,x hi/lo) fragments direct-from-global with
// depth-4 register prefetch -> ZERO barriers in the K-loop. One device-wide
// two-level barrier per step; __threadfence() release (cross-XCD L2 writeback) +
// acquire-spin (L2 invalidate) make the ping-ponged h buffers coherent.
__global__ __launch_bounds__(256, 1) void lstm_persist(
    const unsigned short* __restrict__ xph,   // [SEQ*256][320]
    const unsigned short* __restrict__ xpl,
    const unsigned short* __restrict__ Wph,   // [4096][1344] bf16 hi
    const float* __restrict__ biasp,          // [4096]
    unsigned short* __restrict__ h0h, unsigned short* __restrict__ h0l,  // ping
    unsigned short* __restrict__ h1h, unsigned short* __restrict__ h1l,  // pong
    unsigned int* barcnt)                     // [0]=root, [32+g*32]=group g counter (zeroed)
{
  __shared__ unsigned short wlds[64 * WROW];  // 132096 B
  __shared__ float epi[64 * 65];              // 16640 B (separate from wlds; W persists)

  const int t_   = threadIdx.x;
  const int lane = t_ & 63;
  const int wave = t_ >> 6;
  const int wm   = (wave >> 1) * 32;
  const int wn   = (wave & 1) * 32;
  const int col  = lane & 15;
  const int quad = lane >> 4;
  const int id    = blockIdx.x;
  const int jtile = (id & 7) * 8 + ((id >> 3) & 7);   // XCD-local j grouping
  const int mt_   = id >> 6;
  const int m0 = mt_ * 64, n0 = jtile * 64, j0 = jtile * 16;

  // ---- W_hh tile -> LDS (rows n0..n0+64, k 0..1024), once ----
  for (int i = t_; i < 64 * 128; i += 256) {
    const int row = i >> 7, slot = i & 127;
    *(uint4*)(wlds + row * WROW + slot * 8) =
        *(const uint4*)(Wph + (size_t)(n0 + row) * KT + slot * 8);
  }
  // ---- W_ih tile -> regs (10 k-tiles x 2 n-frags = 80 VGPRs), once ----
  short8 wx[10][2];
#pragma unroll
  for (int kx = 0; kx < 10; ++kx)
#pragma unroll
    for (int nt = 0; nt < 2; ++nt)
      wx[kx][nt] = *(const short8*)(Wph + (size_t)(n0 + wn + nt * 16 + col) * KT
                                    + KH + kx * 32 + quad * 8);

  const float bias0 = biasp[n0 + wn + col];
  const float bias1 = biasp[n0 + wn + 16 + col];

  // epilogue mapping fixed across steps -> cell state lives in these 4 regs
  const int mloc = t_ >> 2;
  const int jl4  = (t_ & 3) * 4;
  float c4[4] = {0.f, 0.f, 0.f, 0.f};

  const int rowA = m0 + wm + col;                                 // mt=0 row (+16 for mt=1)
  const unsigned short* wrow = wlds + (wn + col) * WROW + quad * 8;

  __syncthreads();

  for (int st = 0; st < SEQ; ++st) {
    const unsigned short* hrh = (st & 1) ? h1h : h0h;
    const unsigned short* hrl = (st & 1) ? h1l : h0l;
    unsigned short* hwh = (st & 1) ? h0h : h1h;
    unsigned short* hwl = (st & 1) ? h0l : h1l;
    const unsigned short* xh = xph + (size_t)st * BATCH * KXP;
    const unsigned short* xl = xpl + (size_t)st * BATCH * KXP;

    floatx4 acc[2][2];
#pragma unroll
    for (int i = 0; i < 2; ++i)
#pragma unroll
      for (int j = 0; j < 2; ++j) acc[i][j] = (floatx4){0.f, 0.f, 0.f, 0.f};

    // depth-4 prefetch slots; vt (virtual k-tile) compile-time under full unroll,
    // so all array indices stay static (registers, no scratch).
    short8 pah0[4], pah1[4], pal0[4], pal1[4];

#define LOADA(vt, s) do {                                                     \
      if ((vt) < KTH) {                                                       \
        const int ko = (vt) * 32 + quad * 8;                                  \
        pah0[s] = *(const short8*)(hrh + (size_t)rowA * KH + ko);             \
        pah1[s] = *(const short8*)(hrh + (size_t)(rowA + 16) * KH + ko);      \
        pal0[s] = *(const short8*)(hrl + (size_t)rowA * KH + ko);             \
        pal1[s] = *(const short8*)(hrl + (size_t)(rowA + 16) * KH + ko);      \
      } else {                                                                \
        const int ko = ((vt) - KTH) * 32 + quad * 8;                          \
        pah0[s] = *(const short8*)(xh + (size_t)rowA * KXP + ko);             \
        pah1[s] = *(const short8*)(xh + (size_t)(rowA + 16) * KXP + ko);      \
        pal0[s] = *(const short8*)(xl + (size_t)rowA * KXP + ko);             \
        pal1[s] = *(const short8*)(xl + (size_t)(rowA + 16) * KXP + ko);      \
      } } while (0)

#pragma unroll
    for (int v = 0; v < 4; ++v) LOADA(v, v);

#pragma unroll
    for (int vt = 0; vt < NKT; ++vt) {
      const int s = vt & 3;
      short8 bh0, bh1;
      if (vt < KTH) {
        bh0 = *(const short8*)(wrow + vt * 32);
        bh1 = *(const short8*)(wrow + 16 * WROW + vt * 32);
      } else {
        bh0 = wx[vt - KTH][0];
        bh1 = wx[vt - KTH][1];
      }
      const short8 a0 = pah0[s], a1 = pah1[s], l0 = pal0[s], l1 = pal1[s];
      if (vt + 4 < NKT) LOADA(vt + 4, s);
      mfma2(acc[0][0], a0, l0, bh0);
      mfma2(acc[0][1], a0, l0, bh1);
      mfma2(acc[1][0], a1, l1, bh0);
      mfma2(acc[1][1], a1, l1, bh1);
    }
#undef LOADA

    // ---- epilogue: gates -> epi[n'][m] (+bias), fused cell update ----
    // (prev step's epi reads completed before prev grid barrier -> safe to write)
#pragma unroll
    for (int mt = 0; mt < 2; ++mt)
#pragma unroll
      for (int nt = 0; nt < 2; ++nt) {
        const int nl = wn + nt * 16 + col;
        const float bb = nt ? bias1 : bias0;
#pragma unroll
        for (int reg = 0; reg < 4; ++reg) {
          const int ml = wm + mt * 16 + quad * 4 + reg;
          epi[nl * 65 + ml] = acc[mt][nt][reg] + bb;
        }
      }
    __syncthreads();

    float hn[4];
#pragma unroll
    for (int jj = 0; jj < 4; ++jj) {
      const int nl = (jl4 + jj) * 4;
      const float gi = epi[(nl + 0) * 65 + mloc];
      const float gf = epi[(nl + 1) * 65 + mloc];
      const float gg = epi[(nl + 2) * 65 + mloc];
      const float go = epi[(nl + 3) * 65 + mloc];
      const float cnew = sigf(gf) * c4[jj] + sigf(gi) * tanhfast(gg);
      c4[jj] = cnew;
      hn[jj] = sigf(go) * tanhfast(cnew);
    }
    ushort4 uh, ul;
    uh.x = bf16_rne(hn[0]); uh.y = bf16_rne(hn[1]);
    uh.z = bf16_rne(hn[2]); uh.w = bf16_rne(hn[3]);
    ul.x = bf16_rne(hn[0] - bf16f(uh.x));
    ul.y = bf16_rne(hn[1] - bf16f(uh.y));
    ul.z = bf16_rne(hn[2] - bf16f(uh.z));
    ul.w = bf16_rne(hn[3] - bf16f(uh.w));
    *(ushort4*)(hwh + (size_t)(m0 + mloc) * KH + (j0 + jl4)) = uh;
    *(ushort4*)(hwl + (size_t)(m0 + mloc) * KH + (j0 + jl4)) = ul;

    // ---- device-wide barrier (two-level: 8 groups of 32 -> root) ----
    __syncthreads();   // all block stores drained to L2 (compiler emits vmcnt(0))
    if (t_ == 0) {
      __threadfence();                         // release: XCD L2 writeback -> L3
      unsigned* gc = barcnt + 32 + (id & 7) * 32;   // 128B-spaced group lines
      const unsigned old = atomicAdd(gc, 1u);
      if (old == (unsigned)(st * 32 + 31))     // 32nd arriver of the group
        atomicAdd(barcnt, 1u);
      const unsigned tgt = (unsigned)((st + 1) * 8);
      while (__hip_atomic_load(barcnt, __ATOMIC_ACQUIRE, __HIP_MEMORY_SCOPE_AGENT) < tgt)
        __builtin_amdgcn_s_sleep(2);           // acquire spin: L2 invalidated on exit
    }
    __syncthreads();
  }
}

// ---------------- head GEMM: z = h @ W1^T + b1 (64x64 LDS pipelined, 3-MFMA) ----------------
__global__ __launch_bounds__(256) void head_gemm(
    const unsigned short* __restrict__ Ah_,     // h_hi [256][1024]
    const unsigned short* __restrict__ Al_,
    const unsigned short* __restrict__ Bh_,     // W1 hi [1024][1024]
    const unsigned short* __restrict__ Bl_,
    const float* __restrict__ bias,
    float* __restrict__ C)                      // z [256][1024]
{
  __shared__ short sb[2 * 4 * 2560];

  const int t    = threadIdx.x;
  const int lane = t & 63;
  const int wave = t >> 6;
  const int wm   = (wave >> 1) * 32;
  const int wn   = (wave & 1) * 32;
  const int col  = lane & 15;
  const int quad = lane >> 4;
  const int r    = t >> 2;
  const int k8   = (t & 3) * 8;
  const int m0   = blockIdx.y * 64;
  const int n0   = blockIdx.x * 64;

#define LOAD_TILE(kt, AH, AL, BH, BL) do {                                   \
    const int ka = (kt) * 32 + k8;                                           \
    AH = *(const uint4*)(Ah_ + (size_t)(m0 + r) * KH + ka);                  \
    AL = *(const uint4*)(Al_ + (size_t)(m0 + r) * KH + ka);                  \
    BH = *(const uint4*)(Bh_ + (size_t)(n0 + r) * KH + ka);                  \
    BL = *(const uint4*)(Bl_ + (size_t)(n0 + r) * KH + ka);                  \
  } while (0)

#define STORE_TILE(base, AH, AL, BH, BL) do {                                \
    *(uint4*)((base) +        r * 40 + k8) = AH;                             \
    *(uint4*)((base) + 2560 + r * 40 + k8) = AL;                             \
    *(uint4*)((base) + 5120 + r * 40 + k8) = BH;                             \
    *(uint4*)((base) + 7680 + r * 40 + k8) = BL;                             \
  } while (0)

  floatx4 acc[2][2];
#pragma unroll
  for (int i = 0; i < 2; ++i)
#pragma unroll
    for (int jj = 0; jj < 2; ++jj)
      acc[i][jj] = (floatx4){0.f, 0.f, 0.f, 0.f};

  uint4 cAh, cAl, cBh, cBl, nAh, nAl, nBh, nBl, tAh, tAl, tBh, tBl;
  LOAD_TILE(0, tAh, tAl, tBh, tBl);
  LOAD_TILE(1, cAh, cAl, cBh, cBl);
  STORE_TILE(sb, tAh, tAl, tBh, tBl);

  for (int kt = 0; kt < NKTH; ++kt) {
    if (kt + 2 < NKTH) LOAD_TILE(kt + 2, nAh, nAl, nBh, nBl);
    __syncthreads();
    short* bufp = sb + (kt & 1) * 10240;

    short8 ah[2], al[2], bh[2], bl[2];
#pragma unroll
    for (int mt = 0; mt < 2; ++mt) {
      const int row = (wm + mt * 16 + col) * 40 + quad * 8;
      ah[mt] = *(const short8*)(bufp + row);
      al[mt] = *(const short8*)(bufp + 2560 + row);
    }
#pragma unroll
    for (int nt = 0; nt < 2; ++nt) {
      const int row = (wn + nt * 16 + col) * 40 + quad * 8;
      bh[nt] = *(const short8*)(bufp + 5120 + row);
      bl[nt] = *(const short8*)(bufp + 7680 + row);
    }
#pragma unroll
    for (int mt = 0; mt < 2; ++mt)
#pragma unroll
      for (int nt = 0; nt < 2; ++nt)
        mfma3(acc[mt][nt], ah[mt], al[mt], bh[nt], bl[nt]);

    if (kt + 1 < NKTH) STORE_TILE(sb + ((kt + 1) & 1) * 10240, cAh, cAl, cBh, cBl);
    cAh = nAh; cAl = nAl; cBh = nBh; cBl = nBl;
  }
#undef LOAD_TILE
#undef STORE_TILE

#pragma unroll
  for (int mt = 0; mt < 2; ++mt)
#pragma unroll
    for (int nt = 0; nt < 2; ++nt) {
      const int nl = n0 + wn + nt * 16 + col;
      const float bb = bias[nl];
#pragma unroll
      for (int reg = 0; reg < 4; ++reg) {
        const int ml = m0 + wm + mt * 16 + quad * 4 + reg;
        C[(size_t)ml * LINEARN + nl] = acc[mt][nt][reg] + bb;
      }
    }
}

// ---------------- BN stats ----------------
__global__ __launch_bounds__(64) void bn_stats(
    const float* __restrict__ z, float* __restrict__ mean, float* __restrict__ rstd)
{
  const int n = blockIdx.x;
  const int t = threadIdx.x;
  float s = 0.f, s2 = 0.f;
  for (int r = t; r < BATCH; r += 64) {
    const float v = z[(size_t)r * LINEARN + n];
    s += v; s2 += v * v;
  }
#pragma unroll
  for (int off = 32; off > 0; off >>= 1) {
    s  += __shfl_down(s,  off, 64);
    s2 += __shfl_down(s2, off, 64);
  }
  if (t == 0) {
    const float mm = s * (1.f / BATCH);
    mean[n] = mm;
    rstd[n] = rsqrtf(s2 * (1.f / BATCH) - mm * mm + 1e-5f);
  }
}

// ---------------- head out ----------------
__global__ __launch_bounds__(256) void head_out(
    const float* __restrict__ z, const float* __restrict__ mean, const float* __restrict__ rstd,
    const float* __restrict__ gamma, const float* __restrict__ beta,
    const float* __restrict__ W2, const float* __restrict__ b2, float* __restrict__ out)
{
  const int b = blockIdx.x;
  const int t = threadIdx.x;
  float acc = 0.f;
  for (int n = t; n < LINEARN; n += 256) {
    float v = (z[(size_t)b * LINEARN + n] - mean[n]) * rstd[n] * gamma[n] + beta[n];
    v = fmaxf(v, 0.f);
    acc += v * W2[n];
  }
#pragma unroll
  for (int off = 32; off > 0; off >>= 1) acc += __shfl_down(acc, off, 64);
  __shared__ float ls[4];
  if ((t & 63) == 0) ls[t >> 6] = acc;
  __syncthreads();
  if (t == 0) {
    const float tot = ls[0] + ls[1] + ls[2] + ls[3] + b2[0];
    out[b] = 3.f / (1.f + __expf(-tot));
  }
}

// ---------------- launch ----------------
extern "C" void kernel_launch(void* const* d_in, const int* in_sizes, int n_in,
                              void* d_out, int out_size, void* d_ws, size_t ws_size,
                              hipStream_t stream) {
  const float* x     = (const float*)d_in[0];
  const float* W_ih  = (const float*)d_in[1];
  const float* W_hh  = (const float*)d_in[2];
  const float* b_ih  = (const float*)d_in[3];
  const float* b_hh  = (const float*)d_in[4];
  const float* W1    = (const float*)d_in[5];
  const float* b1    = (const float*)d_in[6];
  const float* gamma = (const float*)d_in[7];
  const float* beta  = (const float*)d_in[8];
  const float* W2    = (const float*)d_in[9];
  const float* b2    = (const float*)d_in[10];
  float* out = (float*)d_out;

  char* w = (char*)d_ws;
  // zero region (contiguous 2 MB): h_hi0, h_lo0, barrier counters (old cst area)
  unsigned short* h_hi0 = (unsigned short*)(w + 0);          // 512 KB
  unsigned short* h_lo0 = (unsigned short*)(w + 524288);     // 512 KB
  unsigned int*   barc  = (unsigned int*)(w + 1048576);      // zeroed each replay
  unsigned short* h_hi1 = (unsigned short*)(w + 2097152);
  unsigned short* h_lo1 = (unsigned short*)(w + 2621440);
  unsigned short* Wph   = (unsigned short*)(w + 3145728);    // 11,010,048 B
  float*          biasp = (float*)(w + 14155776);            // 16 KB
  unsigned short* xph   = (unsigned short*)(w + 14172160);   // 20,971,520 B
  unsigned short* xpl   = (unsigned short*)(w + 35143680);   // 20,971,520 B
  unsigned short* W1ph  = (unsigned short*)(w + 56115200);   // 2 MB
  unsigned short* W1pl  = (unsigned short*)(w + 58212352);   // 2 MB
  float*          z     = (float*)(w + 60309504);            // 1 MB
  float*          mean  = (float*)(w + 61358080);
  float*          rstd  = (float*)(w + 61362176);

  zero_ws<<<512, 256, 0, stream>>>((float4*)w, 131072);
  pack_w<<<(NG * KT + 255) / 256, 256, 0, stream>>>(W_ih, W_hh, Wph);
  pack_bias<<<NG / 256, 256, 0, stream>>>(b_ih, b_hh, biasp);
  pack_x<<<(SEQ * BATCH * KXP + 255) / 256, 256, 0, stream>>>(x, xph, xpl);
  pack_w1<<<(LINEARN * HIDDEN + 255) / 256, 256, 0, stream>>>(W1, W1ph, W1pl);

  // all 128 timesteps in one persistent kernel (grid == 256 CUs, 1 block/CU by LDS)
  lstm_persist<<<256, 256, 0, stream>>>(
      xph, xpl, Wph, biasp, h_hi0, h_lo0, h_hi1, h_lo1, barc);

  // final h (t=127 odd) is in h_hi0/h_lo0
  head_gemm<<<dim3(LINEARN / 64, BATCH / 64), 256, 0, stream>>>(
      h_hi0, h_lo0, W1ph, W1pl, b1, z);
  bn_stats<<<LINEARN, 64, 0, stream>>>(z, mean, rstd);
  head_out<<<BATCH, 256, 0, stream>>>(z, mean, rstd, gamma, beta, W2, b2, out);
}

// Round 3
// 3356.876 us; speedup vs baseline: 1.4762x; 1.4762x over previous
//
#include <hip/hip_runtime.h>
#include <math.h>

// ---------------- constants ----------------
#define SEQ 128
#define BATCH 256
#define INPUT 300
#define HIDDEN 1024
#define NG 4096              // 4*HIDDEN, gate-interleaved: n' = 4*j + gate
#define KH 1024
#define KXP 320              // x K padded 300->320
#define KT 1344              // KH + KXP
#define NKT 42               // KT/32 k-tiles
#define KTH 32               // KH/32 h k-tiles
#define NKTH 32              // head k-tiles (K=1024)
#define LINEARN 1024
#define WROW 1032            // W_hh LDS row stride in shorts (1024 + 8 pad)

typedef __attribute__((ext_vector_type(8))) short short8;
typedef __attribute__((ext_vector_type(4))) float floatx4;

__device__ __forceinline__ float sigf(float x)     { return 1.f / (1.f + __expf(-x)); }
__device__ __forceinline__ float tanhfast(float x) { return 2.f / (1.f + __expf(-2.f * x)) - 1.f; }

__device__ __forceinline__ unsigned short bf16_rne(float f) {
  unsigned u = __float_as_uint(f);
  u += 0x7FFFu + ((u >> 16) & 1u);
  return (unsigned short)(u >> 16);
}
__device__ __forceinline__ float bf16f(unsigned short s) {
  return __uint_as_float(((unsigned)s) << 16);
}

__device__ __forceinline__ void mfma3(floatx4& acc, short8 ah, short8 al, short8 bh, short8 bl) {
  acc = __builtin_amdgcn_mfma_f32_16x16x32_bf16(ah, bh, acc, 0, 0, 0);
  acc = __builtin_amdgcn_mfma_f32_16x16x32_bf16(ah, bl, acc, 0, 0, 0);
  acc = __builtin_amdgcn_mfma_f32_16x16x32_bf16(al, bh, acc, 0, 0, 0);
}
// W kept at bf16 (hi only); A split hi/lo corrects the h/x quantization.
__device__ __forceinline__ void mfma2(floatx4& acc, short8 ah, short8 al, short8 bh) {
  acc = __builtin_amdgcn_mfma_f32_16x16x32_bf16(ah, bh, acc, 0, 0, 0);
  acc = __builtin_amdgcn_mfma_f32_16x16x32_bf16(al, bh, acc, 0, 0, 0);
}

// ---------------- zero ----------------
__global__ __launch_bounds__(256) void zero_ws(float4* p, int n4) {
  int i = blockIdx.x * 256 + threadIdx.x;
  if (i < n4) p[i] = make_float4(0.f, 0.f, 0.f, 0.f);
}

// ---------------- weight pack: gate-interleave + pad, bf16 hi only ----------------
__global__ __launch_bounds__(256) void pack_w(
    const float* __restrict__ W_ih, const float* __restrict__ W_hh,
    unsigned short* __restrict__ Wph)
{
  int id = blockIdx.x * 256 + threadIdx.x;
  if (id >= NG * KT) return;
  int n = id / KT;
  int k = id - n * KT;
  int j = n >> 2, g = n & 3;
  int srow = g * HIDDEN + j;
  float w = 0.f;
  if (k < KH) w = W_hh[(size_t)srow * HIDDEN + k];
  else if (k - KH < INPUT) w = W_ih[(size_t)srow * INPUT + (k - KH)];
  Wph[id] = bf16_rne(w);
}

__global__ __launch_bounds__(256) void pack_bias(
    const float* __restrict__ b_ih, const float* __restrict__ b_hh,
    float* __restrict__ biasp)
{
  int n = blockIdx.x * 256 + threadIdx.x;
  if (n >= NG) return;
  int j = n >> 2, g = n & 3;
  int s = g * HIDDEN + j;
  biasp[n] = b_ih[s] + b_hh[s];
}

// ---------------- pack all x timesteps to bf16 hi/lo, padded 300->320 ----------------
__global__ __launch_bounds__(256) void pack_x(
    const float* __restrict__ x, unsigned short* __restrict__ xph,
    unsigned short* __restrict__ xpl)
{
  int id = blockIdx.x * 256 + threadIdx.x;
  if (id >= SEQ * BATCH * KXP) return;
  int row = id / KXP;
  int k = id - row * KXP;
  float v = (k < INPUT) ? x[(size_t)row * INPUT + k] : 0.f;
  unsigned short hi = bf16_rne(v);
  xph[id] = hi;
  xpl[id] = bf16_rne(v - bf16f(hi));
}

// ---------------- pack W1 (head) hi/lo ----------------
__global__ __launch_bounds__(256) void pack_w1(
    const float* __restrict__ W1, unsigned short* __restrict__ W1ph,
    unsigned short* __restrict__ W1pl)
{
  int id = blockIdx.x * 256 + threadIdx.x;
  if (id >= LINEARN * HIDDEN) return;
  float w = W1[id];
  unsigned short hi = bf16_rne(w);
  W1ph[id] = hi;
  W1pl[id] = bf16_rne(w - bf16f(hi));
}

// ---------------- persistent LSTM: all 128 steps in one kernel ----------------
// 256 blocks (1/CU, pinned by 148.7KB LDS), each owns a fixed 64x64 gate tile.
// W_hh tile resident in LDS (loaded once), W_ih tile in 80 VGPRs, bias in 2 VGPRs,
// cell state c in 4 VGPRs/thread. A (h,x hi/lo) fragments direct-from-global with
// depth-4 register prefetch -> ZERO barriers in the K-loop.
// Per-step device barrier, R1-fixed protocol:
//   release: h written via 8B agent-scope WRITE-THROUGH atomic stores (4KB/block);
//            __syncthreads drains vmcnt(0) -> stores at coherence point; relaxed arrive.
//   spin:    RELAXED agent polls (no cache maintenance per poll!).
//   acquire: ONE agent acquire fence (L1+L2 inv) per block per step after spin exit.
__global__ __launch_bounds__(256, 1) void lstm_persist(
    const unsigned short* __restrict__ xph,   // [SEQ*256][320]
    const unsigned short* __restrict__ xpl,
    const unsigned short* __restrict__ Wph,   // [4096][1344] bf16 hi
    const float* __restrict__ biasp,          // [4096]
    unsigned short* __restrict__ h0h, unsigned short* __restrict__ h0l,  // ping
    unsigned short* __restrict__ h1h, unsigned short* __restrict__ h1l,  // pong
    unsigned int* barcnt)                     // [0]=root, [32+g*32]=group g counter (zeroed)
{
  __shared__ unsigned short wlds[64 * WROW];  // 132096 B
  __shared__ float epi[64 * 65];              // 16640 B (separate from wlds; W persists)

  const int t_   = threadIdx.x;
  const int lane = t_ & 63;
  const int wave = t_ >> 6;
  const int wm   = (wave >> 1) * 32;
  const int wn   = (wave & 1) * 32;
  const int col  = lane & 15;
  const int quad = lane >> 4;
  const int id    = blockIdx.x;
  const int jtile = (id & 7) * 8 + ((id >> 3) & 7);   // XCD-local j grouping
  const int mt_   = id >> 6;
  const int m0 = mt_ * 64, n0 = jtile * 64, j0 = jtile * 16;

  // ---- W_hh tile -> LDS (rows n0..n0+64, k 0..1024), once ----
  for (int i = t_; i < 64 * 128; i += 256) {
    const int row = i >> 7, slot = i & 127;
    *(uint4*)(wlds + row * WROW + slot * 8) =
        *(const uint4*)(Wph + (size_t)(n0 + row) * KT + slot * 8);
  }
  // ---- W_ih tile -> regs (10 k-tiles x 2 n-frags = 80 VGPRs), once ----
  short8 wx[10][2];
#pragma unroll
  for (int kx = 0; kx < 10; ++kx)
#pragma unroll
    for (int nt = 0; nt < 2; ++nt)
      wx[kx][nt] = *(const short8*)(Wph + (size_t)(n0 + wn + nt * 16 + col) * KT
                                    + KH + kx * 32 + quad * 8);

  const float bias0 = biasp[n0 + wn + col];
  const float bias1 = biasp[n0 + wn + 16 + col];

  // epilogue mapping fixed across steps -> cell state lives in these 4 regs
  const int mloc = t_ >> 2;
  const int jl4  = (t_ & 3) * 4;
  float c4[4] = {0.f, 0.f, 0.f, 0.f};

  const int rowA = m0 + wm + col;                                 // mt=0 row (+16 for mt=1)
  const unsigned short* wrow = wlds + (wn + col) * WROW + quad * 8;

  __syncthreads();

  for (int st = 0; st < SEQ; ++st) {
    const unsigned short* hrh = (st & 1) ? h1h : h0h;
    const unsigned short* hrl = (st & 1) ? h1l : h0l;
    unsigned short* hwh = (st & 1) ? h0h : h1h;
    unsigned short* hwl = (st & 1) ? h0l : h1l;
    const unsigned short* xh = xph + (size_t)st * BATCH * KXP;
    const unsigned short* xl = xpl + (size_t)st * BATCH * KXP;

    floatx4 acc[2][2];
#pragma unroll
    for (int i = 0; i < 2; ++i)
#pragma unroll
      for (int j = 0; j < 2; ++j) acc[i][j] = (floatx4){0.f, 0.f, 0.f, 0.f};

    // depth-4 prefetch slots; vt compile-time under full unroll -> static indices.
    short8 pah0[4], pah1[4], pal0[4], pal1[4];

#define LOADA(vt, s) do {                                                     \
      if ((vt) < KTH) {                                                       \
        const int ko = (vt) * 32 + quad * 8;                                  \
        pah0[s] = *(const short8*)(hrh + (size_t)rowA * KH + ko);             \
        pah1[s] = *(const short8*)(hrh + (size_t)(rowA + 16) * KH + ko);      \
        pal0[s] = *(const short8*)(hrl + (size_t)rowA * KH + ko);             \
        pal1[s] = *(const short8*)(hrl + (size_t)(rowA + 16) * KH + ko);      \
      } else {                                                                \
        const int ko = ((vt) - KTH) * 32 + quad * 8;                          \
        pah0[s] = *(const short8*)(xh + (size_t)rowA * KXP + ko);             \
        pah1[s] = *(const short8*)(xh + (size_t)(rowA + 16) * KXP + ko);      \
        pal0[s] = *(const short8*)(xl + (size_t)rowA * KXP + ko);             \
        pal1[s] = *(const short8*)(xl + (size_t)(rowA + 16) * KXP + ko);      \
      } } while (0)

#pragma unroll
    for (int v = 0; v < 4; ++v) LOADA(v, v);

#pragma unroll
    for (int vt = 0; vt < NKT; ++vt) {
      const int s = vt & 3;
      short8 bh0, bh1;
      if (vt < KTH) {
        bh0 = *(const short8*)(wrow + vt * 32);
        bh1 = *(const short8*)(wrow + 16 * WROW + vt * 32);
      } else {
        bh0 = wx[vt - KTH][0];
        bh1 = wx[vt - KTH][1];
      }
      const short8 a0 = pah0[s], a1 = pah1[s], l0 = pal0[s], l1 = pal1[s];
      if (vt + 4 < NKT) LOADA(vt + 4, s);
      mfma2(acc[0][0], a0, l0, bh0);
      mfma2(acc[0][1], a0, l0, bh1);
      mfma2(acc[1][0], a1, l1, bh0);
      mfma2(acc[1][1], a1, l1, bh1);
    }
#undef LOADA

    // ---- epilogue: gates -> epi[n'][m] (+bias), fused cell update ----
#pragma unroll
    for (int mt = 0; mt < 2; ++mt)
#pragma unroll
      for (int nt = 0; nt < 2; ++nt) {
        const int nl = wn + nt * 16 + col;
        const float bb = nt ? bias1 : bias0;
#pragma unroll
        for (int reg = 0; reg < 4; ++reg) {
          const int ml = wm + mt * 16 + quad * 4 + reg;
          epi[nl * 65 + ml] = acc[mt][nt][reg] + bb;
        }
      }
    __syncthreads();

    float hn[4];
#pragma unroll
    for (int jj = 0; jj < 4; ++jj) {
      const int nl = (jl4 + jj) * 4;
      const float gi = epi[(nl + 0) * 65 + mloc];
      const float gf = epi[(nl + 1) * 65 + mloc];
      const float gg = epi[(nl + 2) * 65 + mloc];
      const float go = epi[(nl + 3) * 65 + mloc];
      const float cnew = sigf(gf) * c4[jj] + sigf(gi) * tanhfast(gg);
      c4[jj] = cnew;
      hn[jj] = sigf(go) * tanhfast(cnew);
    }
    // hi parts first (lo derives from hi)
    const unsigned short h0_ = bf16_rne(hn[0]), h1_ = bf16_rne(hn[1]);
    const unsigned short h2_ = bf16_rne(hn[2]), h3_ = bf16_rne(hn[3]);
    const unsigned long long uhv =
        (unsigned long long)h0_ | ((unsigned long long)h1_ << 16) |
        ((unsigned long long)h2_ << 32) | ((unsigned long long)h3_ << 48);
    const unsigned long long ulv =
        (unsigned long long)bf16_rne(hn[0] - bf16f(h0_)) |
        ((unsigned long long)bf16_rne(hn[1] - bf16f(h1_)) << 16) |
        ((unsigned long long)bf16_rne(hn[2] - bf16f(h2_)) << 32) |
        ((unsigned long long)bf16_rne(hn[3] - bf16f(h3_)) << 48);
    // agent-scope write-through stores: h lands at the coherence point, no L2
    // writeback fence needed at release (4KB/block total).
    __hip_atomic_store((unsigned long long*)(hwh + (size_t)(m0 + mloc) * KH + (j0 + jl4)),
                       uhv, __ATOMIC_RELAXED, __HIP_MEMORY_SCOPE_AGENT);
    __hip_atomic_store((unsigned long long*)(hwl + (size_t)(m0 + mloc) * KH + (j0 + jl4)),
                       ulv, __ATOMIC_RELAXED, __HIP_MEMORY_SCOPE_AGENT);

    // ---- device-wide barrier (two-level: 8 groups of 32 -> root) ----
    __syncthreads();   // drains vmcnt(0): all write-through h stores globally visible
    if (t_ == 0) {
      unsigned* gc = barcnt + 32 + (id & 7) * 32;   // 128B-spaced group lines
      const unsigned old =
          __hip_atomic_fetch_add(gc, 1u, __ATOMIC_RELAXED, __HIP_MEMORY_SCOPE_AGENT);
      if (old == (unsigned)(st * 32 + 31))     // 32nd arriver of the group
        __hip_atomic_fetch_add(barcnt, 1u, __ATOMIC_RELAXED, __HIP_MEMORY_SCOPE_AGENT);
      const unsigned tgt = (unsigned)((st + 1) * 8);
      while (__hip_atomic_load(barcnt, __ATOMIC_RELAXED, __HIP_MEMORY_SCOPE_AGENT) < tgt)
        __builtin_amdgcn_s_sleep(2);           // relaxed poll: NO cache maintenance
      // exactly one L1+L2 invalidate per block per step (stale h lines from 2 steps ago)
      __builtin_amdgcn_fence(__ATOMIC_ACQUIRE, "agent");
    }
    __syncthreads();
  }
}

// ---------------- head GEMM: z = h @ W1^T + b1 (64x64 LDS pipelined, 3-MFMA) ----------------
__global__ __launch_bounds__(256) void head_gemm(
    const unsigned short* __restrict__ Ah_,     // h_hi [256][1024]
    const unsigned short* __restrict__ Al_,
    const unsigned short* __restrict__ Bh_,     // W1 hi [1024][1024]
    const unsigned short* __restrict__ Bl_,
    const float* __restrict__ bias,
    float* __restrict__ C)                      // z [256][1024]
{
  __shared__ short sb[2 * 4 * 2560];

  const int t    = threadIdx.x;
  const int lane = t & 63;
  const int wave = t >> 6;
  const int wm   = (wave >> 1) * 32;
  const int wn   = (wave & 1) * 32;
  const int col  = lane & 15;
  const int quad = lane >> 4;
  const int r    = t >> 2;
  const int k8   = (t & 3) * 8;
  const int m0   = blockIdx.y * 64;
  const int n0   = blockIdx.x * 64;

#define LOAD_TILE(kt, AH, AL, BH, BL) do {                                   \
    const int ka = (kt) * 32 + k8;                                           \
    AH = *(const uint4*)(Ah_ + (size_t)(m0 + r) * KH + ka);                  \
    AL = *(const uint4*)(Al_ + (size_t)(m0 + r) * KH + ka);                  \
    BH = *(const uint4*)(Bh_ + (size_t)(n0 + r) * KH + ka);                  \
    BL = *(const uint4*)(Bl_ + (size_t)(n0 + r) * KH + ka);                  \
  } while (0)

#define STORE_TILE(base, AH, AL, BH, BL) do {                                \
    *(uint4*)((base) +        r * 40 + k8) = AH;                             \
    *(uint4*)((base) + 2560 + r * 40 + k8) = AL;                             \
    *(uint4*)((base) + 5120 + r * 40 + k8) = BH;                             \
    *(uint4*)((base) + 7680 + r * 40 + k8) = BL;                             \
  } while (0)

  floatx4 acc[2][2];
#pragma unroll
  for (int i = 0; i < 2; ++i)
#pragma unroll
    for (int jj = 0; jj < 2; ++jj)
      acc[i][jj] = (floatx4){0.f, 0.f, 0.f, 0.f};

  uint4 cAh, cAl, cBh, cBl, nAh, nAl, nBh, nBl, tAh, tAl, tBh, tBl;
  LOAD_TILE(0, tAh, tAl, tBh, tBl);
  LOAD_TILE(1, cAh, cAl, cBh, cBl);
  STORE_TILE(sb, tAh, tAl, tBh, tBl);

  for (int kt = 0; kt < NKTH; ++kt) {
    if (kt + 2 < NKTH) LOAD_TILE(kt + 2, nAh, nAl, nBh, nBl);
    __syncthreads();
    short* bufp = sb + (kt & 1) * 10240;

    short8 ah[2], al[2], bh[2], bl[2];
#pragma unroll
    for (int mt = 0; mt < 2; ++mt) {
      const int row = (wm + mt * 16 + col) * 40 + quad * 8;
      ah[mt] = *(const short8*)(bufp + row);
      al[mt] = *(const short8*)(bufp + 2560 + row);
    }
#pragma unroll
    for (int nt = 0; nt < 2; ++nt) {
      const int row = (wn + nt * 16 + col) * 40 + quad * 8;
      bh[nt] = *(const short8*)(bufp + 5120 + row);
      bl[nt] = *(const short8*)(bufp + 7680 + row);
    }
#pragma unroll
    for (int mt = 0; mt < 2; ++mt)
#pragma unroll
      for (int nt = 0; nt < 2; ++nt)
        mfma3(acc[mt][nt], ah[mt], al[mt], bh[nt], bl[nt]);

    if (kt + 1 < NKTH) STORE_TILE(sb + ((kt + 1) & 1) * 10240, cAh, cAl, cBh, cBl);
    cAh = nAh; cAl = nAl; cBh = nBh; cBl = nBl;
  }
#undef LOAD_TILE
#undef STORE_TILE

#pragma unroll
  for (int mt = 0; mt < 2; ++mt)
#pragma unroll
    for (int nt = 0; nt < 2; ++nt) {
      const int nl = n0 + wn + nt * 16 + col;
      const float bb = bias[nl];
#pragma unroll
      for (int reg = 0; reg < 4; ++reg) {
        const int ml = m0 + wm + mt * 16 + quad * 4 + reg;
        C[(size_t)ml * LINEARN + nl] = acc[mt][nt][reg] + bb;
      }
    }
}

// ---------------- BN stats ----------------
__global__ __launch_bounds__(64) void bn_stats(
    const float* __restrict__ z, float* __restrict__ mean, float* __restrict__ rstd)
{
  const int n = blockIdx.x;
  const int t = threadIdx.x;
  float s = 0.f, s2 = 0.f;
  for (int r = t; r < BATCH; r += 64) {
    const float v = z[(size_t)r * LINEARN + n];
    s += v; s2 += v * v;
  }
#pragma unroll
  for (int off = 32; off > 0; off >>= 1) {
    s  += __shfl_down(s,  off, 64);
    s2 += __shfl_down(s2, off, 64);
  }
  if (t == 0) {
    const float mm = s * (1.f / BATCH);
    mean[n] = mm;
    rstd[n] = rsqrtf(s2 * (1.f / BATCH) - mm * mm + 1e-5f);
  }
}

// ---------------- head out ----------------
__global__ __launch_bounds__(256) void head_out(
    const float* __restrict__ z, const float* __restrict__ mean, const float* __restrict__ rstd,
    const float* __restrict__ gamma, const float* __restrict__ beta,
    const float* __restrict__ W2, const float* __restrict__ b2, float* __restrict__ out)
{
  const int b = blockIdx.x;
  const int t = threadIdx.x;
  float acc = 0.f;
  for (int n = t; n < LINEARN; n += 256) {
    float v = (z[(size_t)b * LINEARN + n] - mean[n]) * rstd[n] * gamma[n] + beta[n];
    v = fmaxf(v, 0.f);
    acc += v * W2[n];
  }
#pragma unroll
  for (int off = 32; off > 0; off >>= 1) acc += __shfl_down(acc, off, 64);
  __shared__ float ls[4];
  if ((t & 63) == 0) ls[t >> 6] = acc;
  __syncthreads();
  if (t == 0) {
    const float tot = ls[0] + ls[1] + ls[2] + ls[3] + b2[0];
    out[b] = 3.f / (1.f + __expf(-tot));
  }
}

// ---------------- launch ----------------
extern "C" void kernel_launch(void* const* d_in, const int* in_sizes, int n_in,
                              void* d_out, int out_size, void* d_ws, size_t ws_size,
                              hipStream_t stream) {
  const float* x     = (const float*)d_in[0];
  const float* W_ih  = (const float*)d_in[1];
  const float* W_hh  = (const float*)d_in[2];
  const float* b_ih  = (const float*)d_in[3];
  const float* b_hh  = (const float*)d_in[4];
  const float* W1    = (const float*)d_in[5];
  const float* b1    = (const float*)d_in[6];
  const float* gamma = (const float*)d_in[7];
  const float* beta  = (const float*)d_in[8];
  const float* W2    = (const float*)d_in[9];
  const float* b2    = (const float*)d_in[10];
  float* out = (float*)d_out;

  char* w = (char*)d_ws;
  // zero region (contiguous 2 MB): h_hi0, h_lo0, barrier counters
  unsigned short* h_hi0 = (unsigned short*)(w + 0);          // 512 KB
  unsigned short* h_lo0 = (unsigned short*)(w + 524288);     // 512 KB
  unsigned int*   barc  = (unsigned int*)(w + 1048576);      // zeroed each replay
  unsigned short* h_hi1 = (unsigned short*)(w + 2097152);
  unsigned short* h_lo1 = (unsigned short*)(w + 2621440);
  unsigned short* Wph   = (unsigned short*)(w + 3145728);    // 11,010,048 B
  float*          biasp = (float*)(w + 14155776);            // 16 KB
  unsigned short* xph   = (unsigned short*)(w + 14172160);   // 20,971,520 B
  unsigned short* xpl   = (unsigned short*)(w + 35143680);   // 20,971,520 B
  unsigned short* W1ph  = (unsigned short*)(w + 56115200);   // 2 MB
  unsigned short* W1pl  = (unsigned short*)(w + 58212352);   // 2 MB
  float*          z     = (float*)(w + 60309504);            // 1 MB
  float*          mean  = (float*)(w + 61358080);
  float*          rstd  = (float*)(w + 61362176);

  zero_ws<<<512, 256, 0, stream>>>((float4*)w, 131072);
  pack_w<<<(NG * KT + 255) / 256, 256, 0, stream>>>(W_ih, W_hh, Wph);
  pack_bias<<<NG / 256, 256, 0, stream>>>(b_ih, b_hh, biasp);
  pack_x<<<(SEQ * BATCH * KXP + 255) / 256, 256, 0, stream>>>(x, xph, xpl);
  pack_w1<<<(LINEARN * HIDDEN + 255) / 256, 256, 0, stream>>>(W1, W1ph, W1pl);

  // all 128 timesteps in one persistent kernel (grid == 256 CUs, 1 block/CU by LDS)
  lstm_persist<<<256, 256, 0, stream>>>(
      xph, xpl, Wph, biasp, h_hi0, h_lo0, h_hi1, h_lo1, barc);

  // final h (t=127 odd) is in h_hi0/h_lo0
  head_gemm<<<dim3(LINEARN / 64, BATCH / 64), 256, 0, stream>>>(
      h_hi0, h_lo0, W1ph, W1pl, b1, z);
  bn_stats<<<LINEARN, 64, 0, stream>>>(z, mean, rstd);
  head_out<<<BATCH, 256, 0, stream>>>(z, mean, rstd, gamma, beta, W2, b2, out);
}

// Round 5
// 2801.072 us; speedup vs baseline: 1.7691x; 1.1984x over previous
//
#include <hip/hip_runtime.h>
#include <math.h>

// ---------------- constants ----------------
#define SEQ 128
#define BATCH 256
#define INPUT 300
#define HIDDEN 1024
#define NG 4096              // 4*HIDDEN, gate-interleaved: n' = 4*j + gate
#define KH 1024
#define KXP 320              // x K padded 300->320
#define KT 1344              // KH + KXP
#define NKT 42               // KT/32 k-tiles
#define KTH 32               // KH/32 h k-tiles
#define NKTH 32              // head k-tiles (K=1024)
#define LINEARN 1024
#define WROW 1032            // W_hh LDS row stride in shorts (1024 + 8 pad)
#define HBSTEP (1u << 20)    // 1MB per h step buffer: [hi 512K][lo 512K]

typedef __attribute__((ext_vector_type(8))) short short8;
typedef __attribute__((ext_vector_type(4))) float floatx4;

__device__ __forceinline__ float sigf(float x)     { return 1.f / (1.f + __expf(-x)); }
__device__ __forceinline__ float tanhfast(float x) { return 2.f / (1.f + __expf(-2.f * x)) - 1.f; }

__device__ __forceinline__ unsigned short bf16_rne(float f) {
  unsigned u = __float_as_uint(f);
  u += 0x7FFFu + ((u >> 16) & 1u);
  return (unsigned short)(u >> 16);
}
__device__ __forceinline__ float bf16f(unsigned short s) {
  return __uint_as_float(((unsigned)s) << 16);
}

__device__ __forceinline__ void mfma3(floatx4& acc, short8 ah, short8 al, short8 bh, short8 bl) {
  acc = __builtin_amdgcn_mfma_f32_16x16x32_bf16(ah, bh, acc, 0, 0, 0);
  acc = __builtin_amdgcn_mfma_f32_16x16x32_bf16(ah, bl, acc, 0, 0, 0);
  acc = __builtin_amdgcn_mfma_f32_16x16x32_bf16(al, bh, acc, 0, 0, 0);
}
// W kept at bf16 (hi only); A split hi/lo corrects the h/x quantization.
__device__ __forceinline__ void mfma2(floatx4& acc, short8 ah, short8 al, short8 bh) {
  acc = __builtin_amdgcn_mfma_f32_16x16x32_bf16(ah, bh, acc, 0, 0, 0);
  acc = __builtin_amdgcn_mfma_f32_16x16x32_bf16(al, bh, acc, 0, 0, 0);
}

// ---------------- zero ----------------
__global__ __launch_bounds__(256) void zero_ws(float4* p, int n4) {
  int i = blockIdx.x * 256 + threadIdx.x;
  if (i < n4) p[i] = make_float4(0.f, 0.f, 0.f, 0.f);
}

// ---------------- weight pack: gate-interleave + pad, bf16 hi only ----------------
__global__ __launch_bounds__(256) void pack_w(
    const float* __restrict__ W_ih, const float* __restrict__ W_hh,
    unsigned short* __restrict__ Wph)
{
  int id = blockIdx.x * 256 + threadIdx.x;
  if (id >= NG * KT) return;
  int n = id / KT;
  int k = id - n * KT;
  int j = n >> 2, g = n & 3;
  int srow = g * HIDDEN + j;
  float w = 0.f;
  if (k < KH) w = W_hh[(size_t)srow * HIDDEN + k];
  else if (k - KH < INPUT) w = W_ih[(size_t)srow * INPUT + (k - KH)];
  Wph[id] = bf16_rne(w);
}

__global__ __launch_bounds__(256) void pack_bias(
    const float* __restrict__ b_ih, const float* __restrict__ b_hh,
    float* __restrict__ biasp)
{
  int n = blockIdx.x * 256 + threadIdx.x;
  if (n >= NG) return;
  int j = n >> 2, g = n & 3;
  int s = g * HIDDEN + j;
  biasp[n] = b_ih[s] + b_hh[s];
}

// ---------------- pack all x timesteps to bf16 hi/lo, padded 300->320 ----------------
__global__ __launch_bounds__(256) void pack_x(
    const float* __restrict__ x, unsigned short* __restrict__ xph,
    unsigned short* __restrict__ xpl)
{
  int id = blockIdx.x * 256 + threadIdx.x;
  if (id >= SEQ * BATCH * KXP) return;
  int row = id / KXP;
  int k = id - row * KXP;
  float v = (k < INPUT) ? x[(size_t)row * INPUT + k] : 0.f;
  unsigned short hi = bf16_rne(v);
  xph[id] = hi;
  xpl[id] = bf16_rne(v - bf16f(hi));
}

// ---------------- pack W1 (head) hi/lo ----------------
__global__ __launch_bounds__(256) void pack_w1(
    const float* __restrict__ W1, unsigned short* __restrict__ W1ph,
    unsigned short* __restrict__ W1pl)
{
  int id = blockIdx.x * 256 + threadIdx.x;
  if (id >= LINEARN * HIDDEN) return;
  float w = W1[id];
  unsigned short hi = bf16_rne(w);
  W1ph[id] = hi;
  W1pl[id] = bf16_rne(w - bf16f(hi));
}

// x-part: acc += x[rows] @ W_ih_tile^T (10 k-tiles, W in regs, cached loads)
__device__ __forceinline__ void xpart(
    const unsigned short* __restrict__ xh, const unsigned short* __restrict__ xl,
    int rowA, int quad, const short8 (&wx)[10][2], floatx4 (&acc)[2][2])
{
  short8 p0[4], p1[4], q0[4], q1[4];
#define LOADX(kx, s) do { const int ko = (kx) * 32 + quad * 8;                \
    p0[s] = *(const short8*)(xh + (size_t)rowA * KXP + ko);                   \
    p1[s] = *(const short8*)(xh + (size_t)(rowA + 16) * KXP + ko);            \
    q0[s] = *(const short8*)(xl + (size_t)rowA * KXP + ko);                   \
    q1[s] = *(const short8*)(xl + (size_t)(rowA + 16) * KXP + ko); } while (0)
#pragma unroll
  for (int v = 0; v < 4; ++v) LOADX(v, v);
#pragma unroll
  for (int kx = 0; kx < 10; ++kx) {
    const int s = kx & 3;
    const short8 a0 = p0[s], a1 = p1[s], l0 = q0[s], l1 = q1[s];
    if (kx + 4 < 10) LOADX(kx + 4, s);
    mfma2(acc[0][0], a0, l0, wx[kx][0]);
    mfma2(acc[0][1], a0, l0, wx[kx][1]);
    mfma2(acc[1][0], a1, l1, wx[kx][0]);
    mfma2(acc[1][1], a1, l1, wx[kx][1]);
  }
#undef LOADX
}

// ---------------- persistent LSTM v2: fresh h buffer per step, NO cache maintenance ----
// Correctness: h[t] lives at a t-unique address. Producer writes via agent-scope
// write-through atomic stores (land at L3 before its barrier arrival). Consumer's L2
// has NEVER cached these addresses this launch -> compulsory miss -> fresh L3 data via
// PLAIN cached dwordx4 loads. No fences, no invalidates, no stale-line hazard.
// (Cross-replay staleness handled by the runtime's dispatch-boundary L2 WB+INV —
// the R0 per-step-launch path relied on exactly this and passed.)
// Swizzle: xcd=id&7 (perf heuristic only), mt=xcd>>1 -> each XCD's 32 blocks share
// one 64-row batch tile; barrier is mt-local (64 blocks, 2-level, own h-rows only).
// x-part (no h dependency) runs between barrier-arrive and barrier-poll to hide
// barrier propagation latency behind MFMA work.
__global__ __launch_bounds__(256, 1) void lstm_persist2(
    const unsigned short* __restrict__ xph,   // [SEQ*256][320]
    const unsigned short* __restrict__ xpl,
    const unsigned short* __restrict__ Wph,   // [4096][1344] bf16 hi
    const float* __restrict__ biasp,          // [4096]
    char* __restrict__ hbase,                 // 129 x 1MB step buffers
    unsigned int* barcnt)                     // root[mt]=barcnt[mt*32]; sub=barcnt[128+xcd*32]
{
  __shared__ unsigned short wlds[64 * WROW];  // 132096 B
  __shared__ float epi[64 * 65];              // 16640 B

  const int t_   = threadIdx.x;
  const int lane = t_ & 63;
  const int wave = t_ >> 6;
  const int wm   = (wave >> 1) * 32;
  const int wn   = (wave & 1) * 32;
  const int col  = lane & 15;
  const int quad = lane >> 4;
  const int id   = blockIdx.x;
  const int xcd  = id & 7;
  const int mt_  = xcd >> 1;                  // 2 XCDs per m-tile
  const int jtile = (xcd & 1) * 32 + (id >> 3);
  const int m0 = mt_ * 64, n0 = jtile * 64, j0 = jtile * 16;

  // ---- W_hh tile -> LDS (rows n0..n0+64, k 0..1024), once ----
  for (int i = t_; i < 64 * 128; i += 256) {
    const int row = i >> 7, slot = i & 127;
    *(uint4*)(wlds + row * WROW + slot * 8) =
        *(const uint4*)(Wph + (size_t)(n0 + row) * KT + slot * 8);
  }
  // ---- W_ih tile -> regs (10 k-tiles x 2 n-frags = 80 VGPRs), once ----
  short8 wx[10][2];
#pragma unroll
  for (int kx = 0; kx < 10; ++kx)
#pragma unroll
    for (int nt = 0; nt < 2; ++nt)
      wx[kx][nt] = *(const short8*)(Wph + (size_t)(n0 + wn + nt * 16 + col) * KT
                                    + KH + kx * 32 + quad * 8);

  const float bias0 = biasp[n0 + wn + col];
  const float bias1 = biasp[n0 + wn + 16 + col];

  const int mloc = t_ >> 2;
  const int jl4  = (t_ & 3) * 4;
  float c4[4] = {0.f, 0.f, 0.f, 0.f};

  const int rowA = m0 + wm + col;
  const unsigned short* wrow = wlds + (wn + col) * WROW + quad * 8;

  __syncthreads();

  floatx4 acc[2][2];
#pragma unroll
  for (int i = 0; i < 2; ++i)
#pragma unroll
    for (int j = 0; j < 2; ++j) acc[i][j] = (floatx4){0.f, 0.f, 0.f, 0.f};
  // prologue: x-part for step 0 (h[0]=0, so acc starts as the x contribution)
  xpart(xph, xpl, rowA, quad, wx, acc);

#pragma unroll 1
  for (int st = 0; st < SEQ; ++st) {
    // ---- wait for h[st] (mt-local barrier; skip st=0: h[0] pre-zeroed) ----
    if (st > 0) {
      if (t_ == 0) {
        const unsigned tgt = (unsigned)(st * 2);
        while (__hip_atomic_load(barcnt + mt_ * 32, __ATOMIC_RELAXED,
                                 __HIP_MEMORY_SCOPE_AGENT) < tgt)
          __builtin_amdgcn_s_sleep(1);
      }
      __syncthreads();
    }

    const unsigned short* hrh = (const unsigned short*)(hbase + (size_t)st * HBSTEP);
    const unsigned short* hrl = hrh + 262144;

    // ---- h-part: 32 k-tiles, plain cached loads (fresh addresses), depth-4 ----
    short8 pah0[4], pah1[4], pal0[4], pal1[4];
#define LOADH(kt, s) do { const int ko = (kt) * 32 + quad * 8;                \
      pah0[s] = *(const short8*)(hrh + (size_t)rowA * KH + ko);               \
      pah1[s] = *(const short8*)(hrh + (size_t)(rowA + 16) * KH + ko);        \
      pal0[s] = *(const short8*)(hrl + (size_t)rowA * KH + ko);               \
      pal1[s] = *(const short8*)(hrl + (size_t)(rowA + 16) * KH + ko); } while (0)
#pragma unroll
    for (int v = 0; v < 4; ++v) LOADH(v, v);
#pragma unroll
    for (int kt = 0; kt < KTH; ++kt) {
      const int s = kt & 3;
      const short8 bh0 = *(const short8*)(wrow + kt * 32);
      const short8 bh1 = *(const short8*)(wrow + 16 * WROW + kt * 32);
      const short8 a0 = pah0[s], a1 = pah1[s], l0 = pal0[s], l1 = pal1[s];
      if (kt + 4 < KTH) LOADH(kt + 4, s);
      mfma2(acc[0][0], a0, l0, bh0);
      mfma2(acc[0][1], a0, l0, bh1);
      mfma2(acc[1][0], a1, l1, bh0);
      mfma2(acc[1][1], a1, l1, bh1);
    }
#undef LOADH

    // ---- epilogue: gates -> epi[n'][m] (+bias), fused cell update ----
#pragma unroll
    for (int mt = 0; mt < 2; ++mt)
#pragma unroll
      for (int nt = 0; nt < 2; ++nt) {
        const int nl = wn + nt * 16 + col;
        const float bb = nt ? bias1 : bias0;
#pragma unroll
        for (int reg = 0; reg < 4; ++reg) {
          const int ml = wm + mt * 16 + quad * 4 + reg;
          epi[nl * 65 + ml] = acc[mt][nt][reg] + bb;
        }
      }
    __syncthreads();

    float hn[4];
#pragma unroll
    for (int jj = 0; jj < 4; ++jj) {
      const int nl = (jl4 + jj) * 4;
      const float gi = epi[(nl + 0) * 65 + mloc];
      const float gf = epi[(nl + 1) * 65 + mloc];
      const float gg = epi[(nl + 2) * 65 + mloc];
      const float go = epi[(nl + 3) * 65 + mloc];
      const float cnew = sigf(gf) * c4[jj] + sigf(gi) * tanhfast(gg);
      c4[jj] = cnew;
      hn[jj] = sigf(go) * tanhfast(cnew);
    }
    const unsigned short h0_ = bf16_rne(hn[0]), h1_ = bf16_rne(hn[1]);
    const unsigned short h2_ = bf16_rne(hn[2]), h3_ = bf16_rne(hn[3]);
    const unsigned long long uhv =
        (unsigned long long)h0_ | ((unsigned long long)h1_ << 16) |
        ((unsigned long long)h2_ << 32) | ((unsigned long long)h3_ << 48);
    const unsigned long long ulv =
        (unsigned long long)bf16_rne(hn[0] - bf16f(h0_)) |
        ((unsigned long long)bf16_rne(hn[1] - bf16f(h1_)) << 16) |
        ((unsigned long long)bf16_rne(hn[2] - bf16f(h2_)) << 32) |
        ((unsigned long long)bf16_rne(hn[3] - bf16f(h3_)) << 48);
    unsigned short* hwh = (unsigned short*)(hbase + (size_t)(st + 1) * HBSTEP);
    unsigned short* hwl = hwh + 262144;
    // write-through to coherence point (L3); vmcnt(0) drain at next __syncthreads
    __hip_atomic_store((unsigned long long*)(hwh + (size_t)(m0 + mloc) * KH + (j0 + jl4)),
                       uhv, __ATOMIC_RELAXED, __HIP_MEMORY_SCOPE_AGENT);
    __hip_atomic_store((unsigned long long*)(hwl + (size_t)(m0 + mloc) * KH + (j0 + jl4)),
                       ulv, __ATOMIC_RELAXED, __HIP_MEMORY_SCOPE_AGENT);

    __syncthreads();   // drains vmcnt(0): all h stores at L3; epi reads complete
    // ---- arrive (mt-local 2-level barrier: 32/XCD -> 2 XCDs -> root[mt]) ----
    if (t_ == 0) {
      unsigned* gc = barcnt + 128 + xcd * 32;
      const unsigned old =
          __hip_atomic_fetch_add(gc, 1u, __ATOMIC_RELAXED, __HIP_MEMORY_SCOPE_AGENT);
      if (old == (unsigned)(st * 32 + 31))
        __hip_atomic_fetch_add(barcnt + mt_ * 32, 1u, __ATOMIC_RELAXED,
                               __HIP_MEMORY_SCOPE_AGENT);
    }
    // ---- x-part for st+1 (no h dependency): hides barrier propagation ----
    if (st + 1 < SEQ) {
#pragma unroll
      for (int i = 0; i < 2; ++i)
#pragma unroll
        for (int j = 0; j < 2; ++j) acc[i][j] = (floatx4){0.f, 0.f, 0.f, 0.f};
      xpart(xph + (size_t)(st + 1) * BATCH * KXP,
            xpl + (size_t)(st + 1) * BATCH * KXP, rowA, quad, wx, acc);
    }
  }
}

// ---------------- OLD per-step kernel (fallback when workspace too small) ----------------
__global__ __launch_bounds__(256) void lstm_step(
    const unsigned short* __restrict__ xp_hi, const unsigned short* __restrict__ xp_lo,
    const unsigned short* __restrict__ h_hi_r, const unsigned short* __restrict__ h_lo_r,
    const unsigned short* __restrict__ Wph, const float* __restrict__ biasp,
    float* __restrict__ cst, unsigned short* __restrict__ h_hi_w,
    unsigned short* __restrict__ h_lo_w)
{
  __shared__ short sb[2 * 7680];
  const int t    = threadIdx.x;
  const int lane = t & 63;
  const int wave = t >> 6;
  const int wm   = (wave >> 1) * 32;
  const int wn   = (wave & 1) * 32;
  const int col  = lane & 15;
  const int quad = lane >> 4;
  const int r    = t >> 2;
  const int k8   = (t & 3) * 8;
  const int id     = blockIdx.x;
  const int jtile  = (id & 7) * 8 + ((id >> 3) & 7);
  const int mt_    = id >> 6;
  const int m0   = mt_ * 64;
  const int n0   = jtile * 64;
  const int j0   = jtile * 16;

#define LOAD_TILE(kt, AH, AL, BH) do {                                       \
    if ((kt) < KTH) {                                                        \
      const int ka = (kt) * 32 + k8;                                         \
      AH = *(const uint4*)(h_hi_r + (size_t)(m0 + r) * KH + ka);             \
      AL = *(const uint4*)(h_lo_r + (size_t)(m0 + r) * KH + ka);             \
    } else {                                                                 \
      const int kx = ((kt) - KTH) * 32 + k8;                                 \
      AH = *(const uint4*)(xp_hi + (size_t)(m0 + r) * KXP + kx);             \
      AL = *(const uint4*)(xp_lo + (size_t)(m0 + r) * KXP + kx);             \
    }                                                                        \
    BH = *(const uint4*)(Wph + (size_t)(n0 + r) * KT + (kt) * 32 + k8);      \
  } while (0)
#define STORE_TILE(base, AH, AL, BH) do {                                    \
    *(uint4*)((base) +        r * 40 + k8) = AH;                             \
    *(uint4*)((base) + 2560 + r * 40 + k8) = AL;                             \
    *(uint4*)((base) + 5120 + r * 40 + k8) = BH;                             \
  } while (0)

  floatx4 acc[2][2];
#pragma unroll
  for (int i = 0; i < 2; ++i)
#pragma unroll
    for (int jj = 0; jj < 2; ++jj)
      acc[i][jj] = (floatx4){0.f, 0.f, 0.f, 0.f};

  uint4 cAh, cAl, cBh, nAh, nAl, nBh, tAh, tAl, tBh;
  LOAD_TILE(0, tAh, tAl, tBh);
  LOAD_TILE(1, cAh, cAl, cBh);
  STORE_TILE(sb, tAh, tAl, tBh);

  for (int kt = 0; kt < NKT; ++kt) {
    if (kt + 2 < NKT) LOAD_TILE(kt + 2, nAh, nAl, nBh);
    __syncthreads();
    short* bufp = sb + (kt & 1) * 7680;
    short8 ah[2], al[2], bh[2];
#pragma unroll
    for (int mt = 0; mt < 2; ++mt) {
      const int row = (wm + mt * 16 + col) * 40 + quad * 8;
      ah[mt] = *(const short8*)(bufp + row);
      al[mt] = *(const short8*)(bufp + 2560 + row);
    }
#pragma unroll
    for (int nt = 0; nt < 2; ++nt) {
      const int row = (wn + nt * 16 + col) * 40 + quad * 8;
      bh[nt] = *(const short8*)(bufp + 5120 + row);
    }
#pragma unroll
    for (int mt = 0; mt < 2; ++mt)
#pragma unroll
      for (int nt = 0; nt < 2; ++nt)
        mfma2(acc[mt][nt], ah[mt], al[mt], bh[nt]);
    if (kt + 1 < NKT) STORE_TILE(sb + ((kt + 1) & 1) * 7680, cAh, cAl, cBh);
    cAh = nAh; cAl = nAl; cBh = nBh;
  }
#undef LOAD_TILE
#undef STORE_TILE

  __syncthreads();
  float* epi = (float*)sb;
#pragma unroll
  for (int mt = 0; mt < 2; ++mt)
#pragma unroll
    for (int nt = 0; nt < 2; ++nt) {
      const int nl = wn + nt * 16 + col;
      const float bb = biasp[n0 + nl];
#pragma unroll
      for (int reg = 0; reg < 4; ++reg) {
        const int ml = wm + mt * 16 + quad * 4 + reg;
        epi[nl * 65 + ml] = acc[mt][nt][reg] + bb;
      }
    }
  __syncthreads();

  const int mloc = t >> 2;
  const int jl4  = (t & 3) * 4;
  const int m    = m0 + mloc;
  const int j    = j0 + jl4;
  float4 cold = *(const float4*)(cst + (size_t)m * HIDDEN + j);
  float cn[4], hn[4];
#pragma unroll
  for (int jj = 0; jj < 4; ++jj) {
    const int nl = (jl4 + jj) * 4;
    const float gi = epi[(nl + 0) * 65 + mloc];
    const float gf = epi[(nl + 1) * 65 + mloc];
    const float gg = epi[(nl + 2) * 65 + mloc];
    const float go = epi[(nl + 3) * 65 + mloc];
    const float cc = (jj == 0) ? cold.x : (jj == 1) ? cold.y : (jj == 2) ? cold.z : cold.w;
    const float cnew = sigf(gf) * cc + sigf(gi) * tanhfast(gg);
    cn[jj] = cnew;
    hn[jj] = sigf(go) * tanhfast(cnew);
  }
  *(float4*)(cst + (size_t)m * HIDDEN + j) = make_float4(cn[0], cn[1], cn[2], cn[3]);
  ushort4 uh, ul;
  uh.x = bf16_rne(hn[0]); uh.y = bf16_rne(hn[1]); uh.z = bf16_rne(hn[2]); uh.w = bf16_rne(hn[3]);
  ul.x = bf16_rne(hn[0] - bf16f(uh.x));
  ul.y = bf16_rne(hn[1] - bf16f(uh.y));
  ul.z = bf16_rne(hn[2] - bf16f(uh.z));
  ul.w = bf16_rne(hn[3] - bf16f(uh.w));
  *(ushort4*)(h_hi_w + (size_t)m * HIDDEN + j) = uh;
  *(ushort4*)(h_lo_w + (size_t)m * HIDDEN + j) = ul;
}

// ---------------- head GEMM: z = h @ W1^T + b1 (64x64 LDS pipelined, 3-MFMA) ----------------
__global__ __launch_bounds__(256) void head_gemm(
    const unsigned short* __restrict__ Ah_,     // h_hi [256][1024]
    const unsigned short* __restrict__ Al_,
    const unsigned short* __restrict__ Bh_,     // W1 hi [1024][1024]
    const unsigned short* __restrict__ Bl_,
    const float* __restrict__ bias,
    float* __restrict__ C)                      // z [256][1024]
{
  __shared__ short sb[2 * 4 * 2560];

  const int t    = threadIdx.x;
  const int lane = t & 63;
  const int wave = t >> 6;
  const int wm   = (wave >> 1) * 32;
  const int wn   = (wave & 1) * 32;
  const int col  = lane & 15;
  const int quad = lane >> 4;
  const int r    = t >> 2;
  const int k8   = (t & 3) * 8;
  const int m0   = blockIdx.y * 64;
  const int n0   = blockIdx.x * 64;

#define LOAD_TILE(kt, AH, AL, BH, BL) do {                                   \
    const int ka = (kt) * 32 + k8;                                           \
    AH = *(const uint4*)(Ah_ + (size_t)(m0 + r) * KH + ka);                  \
    AL = *(const uint4*)(Al_ + (size_t)(m0 + r) * KH + ka);                  \
    BH = *(const uint4*)(Bh_ + (size_t)(n0 + r) * KH + ka);                  \
    BL = *(const uint4*)(Bl_ + (size_t)(n0 + r) * KH + ka);                  \
  } while (0)

#define STORE_TILE(base, AH, AL, BH, BL) do {                                \
    *(uint4*)((base) +        r * 40 + k8) = AH;                             \
    *(uint4*)((base) + 2560 + r * 40 + k8) = AL;                             \
    *(uint4*)((base) + 5120 + r * 40 + k8) = BH;                             \
    *(uint4*)((base) + 7680 + r * 40 + k8) = BL;                             \
  } while (0)

  floatx4 acc[2][2];
#pragma unroll
  for (int i = 0; i < 2; ++i)
#pragma unroll
    for (int jj = 0; jj < 2; ++jj)
      acc[i][jj] = (floatx4){0.f, 0.f, 0.f, 0.f};

  uint4 cAh, cAl, cBh, cBl, nAh, nAl, nBh, nBl, tAh, tAl, tBh, tBl;
  LOAD_TILE(0, tAh, tAl, tBh, tBl);
  LOAD_TILE(1, cAh, cAl, cBh, cBl);
  STORE_TILE(sb, tAh, tAl, tBh, tBl);

  for (int kt = 0; kt < NKTH; ++kt) {
    if (kt + 2 < NKTH) LOAD_TILE(kt + 2, nAh, nAl, nBh, nBl);
    __syncthreads();
    short* bufp = sb + (kt & 1) * 10240;

    short8 ah[2], al[2], bh[2], bl[2];
#pragma unroll
    for (int mt = 0; mt < 2; ++mt) {
      const int row = (wm + mt * 16 + col) * 40 + quad * 8;
      ah[mt] = *(const short8*)(bufp + row);
      al[mt] = *(const short8*)(bufp + 2560 + row);
    }
#pragma unroll
    for (int nt = 0; nt < 2; ++nt) {
      const int row = (wn + nt * 16 + col) * 40 + quad * 8;
      bh[nt] = *(const short8*)(bufp + 5120 + row);
      bl[nt] = *(const short8*)(bufp + 7680 + row);
    }
#pragma unroll
    for (int mt = 0; mt < 2; ++mt)
#pragma unroll
      for (int nt = 0; nt < 2; ++nt)
        mfma3(acc[mt][nt], ah[mt], al[mt], bh[nt], bl[nt]);

    if (kt + 1 < NKTH) STORE_TILE(sb + ((kt + 1) & 1) * 10240, cAh, cAl, cBh, cBl);
    cAh = nAh; cAl = nAl; cBh = nBh; cBl = nBl;
  }
#undef LOAD_TILE
#undef STORE_TILE

#pragma unroll
  for (int mt = 0; mt < 2; ++mt)
#pragma unroll
    for (int nt = 0; nt < 2; ++nt) {
      const int nl = n0 + wn + nt * 16 + col;
      const float bb = bias[nl];
#pragma unroll
      for (int reg = 0; reg < 4; ++reg) {
        const int ml = m0 + wm + mt * 16 + quad * 4 + reg;
        C[(size_t)ml * LINEARN + nl] = acc[mt][nt][reg] + bb;
      }
    }
}

// ---------------- BN stats ----------------
__global__ __launch_bounds__(64) void bn_stats(
    const float* __restrict__ z, float* __restrict__ mean, float* __restrict__ rstd)
{
  const int n = blockIdx.x;
  const int t = threadIdx.x;
  float s = 0.f, s2 = 0.f;
  for (int r = t; r < BATCH; r += 64) {
    const float v = z[(size_t)r * LINEARN + n];
    s += v; s2 += v * v;
  }
#pragma unroll
  for (int off = 32; off > 0; off >>= 1) {
    s  += __shfl_down(s,  off, 64);
    s2 += __shfl_down(s2, off, 64);
  }
  if (t == 0) {
    const float mm = s * (1.f / BATCH);
    mean[n] = mm;
    rstd[n] = rsqrtf(s2 * (1.f / BATCH) - mm * mm + 1e-5f);
  }
}

// ---------------- head out ----------------
__global__ __launch_bounds__(256) void head_out(
    const float* __restrict__ z, const float* __restrict__ mean, const float* __restrict__ rstd,
    const float* __restrict__ gamma, const float* __restrict__ beta,
    const float* __restrict__ W2, const float* __restrict__ b2, float* __restrict__ out)
{
  const int b = blockIdx.x;
  const int t = threadIdx.x;
  float acc = 0.f;
  for (int n = t; n < LINEARN; n += 256) {
    float v = (z[(size_t)b * LINEARN + n] - mean[n]) * rstd[n] * gamma[n] + beta[n];
    v = fmaxf(v, 0.f);
    acc += v * W2[n];
  }
#pragma unroll
  for (int off = 32; off > 0; off >>= 1) acc += __shfl_down(acc, off, 64);
  __shared__ float ls[4];
  if ((t & 63) == 0) ls[t >> 6] = acc;
  __syncthreads();
  if (t == 0) {
    const float tot = ls[0] + ls[1] + ls[2] + ls[3] + b2[0];
    out[b] = 3.f / (1.f + __expf(-tot));
  }
}

// ---------------- launch ----------------
extern "C" void kernel_launch(void* const* d_in, const int* in_sizes, int n_in,
                              void* d_out, int out_size, void* d_ws, size_t ws_size,
                              hipStream_t stream) {
  const float* x     = (const float*)d_in[0];
  const float* W_ih  = (const float*)d_in[1];
  const float* W_hh  = (const float*)d_in[2];
  const float* b_ih  = (const float*)d_in[3];
  const float* b_hh  = (const float*)d_in[4];
  const float* W1    = (const float*)d_in[5];
  const float* b1    = (const float*)d_in[6];
  const float* gamma = (const float*)d_in[7];
  const float* beta  = (const float*)d_in[8];
  const float* W2    = (const float*)d_in[9];
  const float* b2    = (const float*)d_in[10];
  float* out = (float*)d_out;
  char* w = (char*)d_ws;

  // new-path layout
  const size_t HB_OFF   = 0;                     // 129 x 1MB = 135,266,304
  const size_t BARC_OFF = 135266304;             // 4 KB
  const size_t WPH_OFF  = 135270400;             // 11,010,048
  const size_t BIAS_OFF = 146280448;             // 16 KB
  const size_t XPH_OFF  = 146296832;             // 20,971,520
  const size_t XPL_OFF  = 167268352;             // 20,971,520
  const size_t W1PH_OFF = 188239872;             // 2 MB
  const size_t W1PL_OFF = 190337024;             // 2 MB
  const size_t Z_OFF    = 192434176;             // 1 MB
  const size_t MEAN_OFF = 193482752;
  const size_t RSTD_OFF = 193486848;
  const size_t NEED     = 193490944;

  if (ws_size >= NEED) {
    unsigned short* Wph   = (unsigned short*)(w + WPH_OFF);
    float*          biasp = (float*)(w + BIAS_OFF);
    unsigned short* xph   = (unsigned short*)(w + XPH_OFF);
    unsigned short* xpl   = (unsigned short*)(w + XPL_OFF);
    unsigned short* W1ph  = (unsigned short*)(w + W1PH_OFF);
    unsigned short* W1pl  = (unsigned short*)(w + W1PL_OFF);
    float*          z     = (float*)(w + Z_OFF);
    float*          mean  = (float*)(w + MEAN_OFF);
    float*          rstd  = (float*)(w + RSTD_OFF);

    zero_ws<<<256, 256, 0, stream>>>((float4*)(w + HB_OFF), 65536);      // h[0] = 0
    zero_ws<<<1, 256, 0, stream>>>((float4*)(w + BARC_OFF), 256);        // barrier counters
    pack_w<<<(NG * KT + 255) / 256, 256, 0, stream>>>(W_ih, W_hh, Wph);
    pack_bias<<<NG / 256, 256, 0, stream>>>(b_ih, b_hh, biasp);
    pack_x<<<(SEQ * BATCH * KXP + 255) / 256, 256, 0, stream>>>(x, xph, xpl);
    pack_w1<<<(LINEARN * HIDDEN + 255) / 256, 256, 0, stream>>>(W1, W1ph, W1pl);

    lstm_persist2<<<256, 256, 0, stream>>>(
        xph, xpl, Wph, biasp, w + HB_OFF, (unsigned int*)(w + BARC_OFF));

    const unsigned short* hfh = (const unsigned short*)(w + HB_OFF + (size_t)SEQ * HBSTEP);
    const unsigned short* hfl = hfh + 262144;
    head_gemm<<<dim3(LINEARN / 64, BATCH / 64), 256, 0, stream>>>(
        hfh, hfl, W1ph, W1pl, b1, z);
    bn_stats<<<LINEARN, 64, 0, stream>>>(z, mean, rstd);
    head_out<<<BATCH, 256, 0, stream>>>(z, mean, rstd, gamma, beta, W2, b2, out);
  } else {
    // -------- fallback: verified 128-launch path (R0 layout) --------
    unsigned short* h_hi0 = (unsigned short*)(w + 0);
    unsigned short* h_lo0 = (unsigned short*)(w + 524288);
    float*          cst   = (float*)(w + 1048576);
    unsigned short* h_hi1 = (unsigned short*)(w + 2097152);
    unsigned short* h_lo1 = (unsigned short*)(w + 2621440);
    unsigned short* Wph   = (unsigned short*)(w + 3145728);
    float*          biasp = (float*)(w + 14155776);
    unsigned short* xph   = (unsigned short*)(w + 14172160);
    unsigned short* xpl   = (unsigned short*)(w + 35143680);
    unsigned short* W1ph  = (unsigned short*)(w + 56115200);
    unsigned short* W1pl  = (unsigned short*)(w + 58212352);
    float*          z     = (float*)(w + 60309504);
    float*          mean  = (float*)(w + 61358080);
    float*          rstd  = (float*)(w + 61362176);

    zero_ws<<<512, 256, 0, stream>>>((float4*)w, 131072);
    pack_w<<<(NG * KT + 255) / 256, 256, 0, stream>>>(W_ih, W_hh, Wph);
    pack_bias<<<NG / 256, 256, 0, stream>>>(b_ih, b_hh, biasp);
    pack_x<<<(SEQ * BATCH * KXP + 255) / 256, 256, 0, stream>>>(x, xph, xpl);
    pack_w1<<<(LINEARN * HIDDEN + 255) / 256, 256, 0, stream>>>(W1, W1ph, W1pl);

    for (int t = 0; t < SEQ; ++t) {
      const unsigned short* hr_hi = (t & 1) ? h_hi1 : h_hi0;
      const unsigned short* hr_lo = (t & 1) ? h_lo1 : h_lo0;
      unsigned short* hw_hi = (t & 1) ? h_hi0 : h_hi1;
      unsigned short* hw_lo = (t & 1) ? h_lo0 : h_lo1;
      lstm_step<<<256, 256, 0, stream>>>(
          xph + (size_t)t * BATCH * KXP, xpl + (size_t)t * BATCH * KXP,
          hr_hi, hr_lo, Wph, biasp, cst, hw_hi, hw_lo);
    }
    head_gemm<<<dim3(LINEARN / 64, BATCH / 64), 256, 0, stream>>>(
        h_hi0, h_lo0, W1ph, W1pl, b1, z);
    bn_stats<<<LINEARN, 64, 0, stream>>>(z, mean, rstd);
    head_out<<<BATCH, 256, 0, stream>>>(z, mean, rstd, gamma, beta, W2, b2, out);
  }
}